// Round 4
// baseline (4205.255 us; speedup 1.0000x reference)
//
#include <hip/hip_runtime.h>
#include <math.h>

// Problem constants
#define DD 256            // latent dim
#define KK 8192           // codebook size
#define NN 16384          // 16 * 1024 rows
#define RPB 32            // rows per block (4 waves x 8 rows)
#define RPW 8             // rows per wave
#define NT 64             // codebook cols per chunk (= lanes)
#define NCHUNK (KK / NT)  // 128
#define NBLOCKS (NN / RPB)  // 512
#define CSTRIDE 260       // 65 16B-units/row, odd -> 2-way (free) b128 column reads
#define MT 64             // rows per block in rowsumsq

// Output layout (all float32, concatenated in reference return order)
#define OUT_IDS   0
#define OUT_Q     16384
#define OUT_ST    4210688          // 16384 + 4194304
#define OUT_COMMIT 8404992
#define OUT_CBL    8404993
#define OUT_PERP   8404994

// ---------------------------------------------------------------------------
// async global->LDS, 16B per lane. LDS dest is wave-uniform base + lane*16.
// ---------------------------------------------------------------------------
__device__ __forceinline__ void gl2lds16(const float* g, float* l) {
    __builtin_amdgcn_global_load_lds(
        (const __attribute__((address_space(1))) float*)g,
        (__attribute__((address_space(3))) float*)l, 16, 0, 0);
}

// ---------------------------------------------------------------------------
// numpy pairwise-sum replica for sum of squares (verified bit-exact, round 2)
// ---------------------------------------------------------------------------
__device__ __forceinline__ float np_block128_sumsq(const float* p) {
    #pragma clang fp contract(off)
    float r0 = p[0] * p[0], r1 = p[1] * p[1], r2 = p[2] * p[2], r3 = p[3] * p[3];
    float r4 = p[4] * p[4], r5 = p[5] * p[5], r6 = p[6] * p[6], r7 = p[7] * p[7];
    for (int i = 8; i < 128; i += 8) {
        r0 = r0 + p[i + 0] * p[i + 0];
        r1 = r1 + p[i + 1] * p[i + 1];
        r2 = r2 + p[i + 2] * p[i + 2];
        r3 = r3 + p[i + 3] * p[i + 3];
        r4 = r4 + p[i + 4] * p[i + 4];
        r5 = r5 + p[i + 5] * p[i + 5];
        r6 = r6 + p[i + 6] * p[i + 6];
        r7 = r7 + p[i + 7] * p[i + 7];
    }
    return ((r0 + r1) + (r2 + r3)) + ((r4 + r5) + (r6 + r7));
}

__device__ __forceinline__ float np_pairwise256_sumsq(const float* a) {
    #pragma clang fp contract(off)
    float s0 = np_block128_sumsq(a);
    float s1 = np_block128_sumsq(a + 128);
    return s0 + s1;
}

// ---------------------------------------------------------------------------
// Kernel 1: per-row sum of squares, numpy-pairwise-exact (unchanged, verified)
// ---------------------------------------------------------------------------
__global__ __launch_bounds__(256) void rowsumsq(const float* __restrict__ A,
                                                float* __restrict__ out) {
    __shared__ __align__(16) float sA[MT][CSTRIDE];
    const int tid = threadIdx.x;
    const int base = blockIdx.x * MT;
    #pragma unroll
    for (int i = 0; i < 16; ++i) {
        int g = i * 256 + tid;
        int row = g >> 6, d4 = g & 63;
        float4 v = reinterpret_cast<const float4*>(A)[(size_t)(base + row) * (DD / 4) + d4];
        *reinterpret_cast<float4*>(&sA[row][d4 * 4]) = v;
    }
    __syncthreads();
    if (tid < MT) out[base + tid] = np_pairwise256_sumsq(sA[tid]);
}

// ---------------------------------------------------------------------------
// Kernel 2: main VQ kernel. 512 blocks x 256 threads, 2 blocks/CU.
//   wave w owns 8 rows. X read via VECTOR loads (vmcnt) with wave-identical
//   addresses -> one L1 line per load, broadcast, deeply pipelined, decoupled
//   from the ds_read lgkmcnt waits. (Round-3's scalar s_load path shared
//   lgkmcnt with ds_read -> serializing waits -> VALUBusy 32%.)
//   lanes own 64 codebook cols/chunk; C staged via global_load_lds (async).
//   per-(row,col) fp32 fma chain identical to round 2/3 (bit-exact, verified).
// ---------------------------------------------------------------------------
__global__ __launch_bounds__(256, 2) void vq_main(const float* __restrict__ X,
                                                  const float* __restrict__ CB,
                                                  const float* __restrict__ c2,
                                                  const float* __restrict__ x2,
                                                  const float* __restrict__ mask,
                                                  float* __restrict__ out,
                                                  float* __restrict__ hist,
                                                  float* __restrict__ partial) {
    __shared__ __align__(16) float sC[NT][CSTRIDE];   // 66560 B -> 2 blocks/CU
    __shared__ int   sIdi[RPB];
    __shared__ float wsum[4];

    const int tid  = threadIdx.x;
    const int lane = tid & 63;
    // divergent-typed wave id for the COMPUTE path: keeps X addresses in VGPRs
    // -> global_load_dwordx4 (vmcnt), not s_load (lgkmcnt). Do NOT scalarize.
    const int wid  = tid >> 6;
    // uniform wave id ONLY for the staging LDS destination (builtin needs it)
    const int widu = __builtin_amdgcn_readfirstlane(tid >> 6);
    const int block_row = blockIdx.x * RPB;
    const int wrow = block_row + wid * RPW;

    const float* __restrict__ xw = X + (size_t)wrow * DD;  // same value all lanes

    // ---- stage chunk 0 (each wave stages 16 rows) ----
    #pragma unroll
    for (int i = 0; i < 16; ++i) {
        int n = widu * 16 + i;
        gl2lds16(CB + (size_t)n * DD + lane * 4, &sC[n][0]);
    }

    // x2 row constants (vector loads, broadcast)
    float x2r[RPW];
    #pragma unroll
    for (int r = 0; r < RPW; ++r) x2r[r] = x2[wrow + r];

    __syncthreads();   // drains vmcnt -> chunk 0 resident

    float best[RPW];
    int   besti[RPW];
    #pragma unroll
    for (int r = 0; r < RPW; ++r) { best[r] = 3.4e38f; besti[r] = 0; }

    for (int chunk = 0; chunk < NCHUNK; ++chunk) {
        const int col = chunk * NT + lane;
        const float c2v = c2[col];

        float acc[RPW];
        #pragma unroll
        for (int r = 0; r < RPW; ++r) acc[r] = 0.0f;

        // in-order fma chain per (row, col) over d = 0..255: bit-exact
        #pragma unroll 4
        for (int d4 = 0; d4 < DD / 4; ++d4) {
            float4 cc = *reinterpret_cast<const float4*>(&sC[lane][d4 * 4]);
            #pragma unroll
            for (int r = 0; r < RPW; ++r) {
                float4 xs = *reinterpret_cast<const float4*>(xw + r * DD + d4 * 4);
                acc[r] = fmaf(xs.x, cc.x, acc[r]);
                acc[r] = fmaf(xs.y, cc.y, acc[r]);
                acc[r] = fmaf(xs.z, cc.z, acc[r]);
                acc[r] = fmaf(xs.w, cc.w, acc[r]);
            }
        }

        // fp32 distance exactly as numpy: fl(fl(x2+c2) - 2m), first-index ties
        #pragma unroll
        for (int r = 0; r < RPW; ++r) {
            float t1 = x2r[r] + c2v;
            float s  = t1 - 2.0f * acc[r];
            if (s < best[r] || (s == best[r] && col < besti[r])) {
                best[r] = s; besti[r] = col;
            }
        }

        __syncthreads();   // all waves done reading sC
        if (chunk + 1 < NCHUNK) {
            const int ncol0 = (chunk + 1) * NT;
            #pragma unroll
            for (int i = 0; i < 16; ++i) {
                int n = widu * 16 + i;
                gl2lds16(CB + (size_t)(ncol0 + n) * DD + lane * 4, &sC[n][0]);
            }
        }
        __syncthreads();   // drain -> next chunk resident (other block covers stall)
    }

    // ---- per-row argmin across the wave's 64 lanes (first-index tie-break) ----
    #pragma unroll
    for (int r = 0; r < RPW; ++r) {
        float b = best[r];
        int  bi = besti[r];
        #pragma unroll
        for (int off = 32; off > 0; off >>= 1) {
            float b2 = __shfl_down(b, off, 64);
            int   i2 = __shfl_down(bi, off, 64);
            if (b2 < b || (b2 == b && i2 < bi)) { b = b2; bi = i2; }
        }
        if (lane == 0) sIdi[wid * RPW + r] = bi;
    }
    __syncthreads();

    if (tid < RPB) {
        int bi = sIdi[tid];
        out[OUT_IDS + block_row + tid] = (float)bi;
        atomicAdd(&hist[bi], mask[block_row + tid]);
    }

    // ---- fused gather: quantized, st_quantized, MSE partial ----
    float msep = 0.0f;
    float* outq  = out + OUT_Q;
    float* outst = out + OUT_ST;
    #pragma unroll
    for (int i = 0; i < 8; ++i) {
        int g = i * 256 + tid;          // 0..2047 covers 32 rows x 64 float4
        int row = g >> 6;
        int d4  = g & 63;
        int id  = sIdi[row];
        float4 q = reinterpret_cast<const float4*>(CB)[(size_t)id * (DD / 4) + d4];
        float4 x = reinterpret_cast<const float4*>(X)[(size_t)(block_row + row) * (DD / 4) + d4];
        float4 st;
        st.x = x.x + (q.x - x.x);
        st.y = x.y + (q.y - x.y);
        st.z = x.z + (q.z - x.z);
        st.w = x.w + (q.w - x.w);
        float dx = x.x - q.x; msep = fmaf(dx, dx, msep);
        dx = x.y - q.y; msep = fmaf(dx, dx, msep);
        dx = x.z - q.z; msep = fmaf(dx, dx, msep);
        dx = x.w - q.w; msep = fmaf(dx, dx, msep);
        size_t o = (size_t)(block_row + row) * (DD / 4) + d4;
        reinterpret_cast<float4*>(outq)[o]  = q;
        reinterpret_cast<float4*>(outst)[o] = st;
    }
    #pragma unroll
    for (int off = 32; off > 0; off >>= 1) msep += __shfl_down(msep, off, 64);
    if (lane == 0) wsum[wid] = msep;
    __syncthreads();
    if (tid == 0) partial[blockIdx.x] = wsum[0] + wsum[1] + wsum[2] + wsum[3];
}

// ---------------------------------------------------------------------------
// Kernel 3: finalize losses + perplexity (double precision, single block)
// ---------------------------------------------------------------------------
__global__ __launch_bounds__(256) void vq_finalize(const float* __restrict__ partial,
                                                   const float* __restrict__ hist,
                                                   float* __restrict__ out) {
    __shared__ double red[256];
    const int tid = threadIdx.x;

    double ps = 0.0;
    for (int j = tid; j < NBLOCKS; j += 256) ps += (double)partial[j];
    red[tid] = ps;
    __syncthreads();
    for (int s = 128; s > 0; s >>= 1) {
        if (tid < s) red[tid] += red[tid + s];
        __syncthreads();
    }
    double mse_sum = red[0];
    __syncthreads();

    double hs = 0.0;
    for (int j = tid; j < KK; j += 256) hs += (double)hist[j];
    red[tid] = hs;
    __syncthreads();
    for (int s = 128; s > 0; s >>= 1) {
        if (tid < s) red[tid] += red[tid + s];
        __syncthreads();
    }
    double denom = red[0] > 1.0 ? red[0] : 1.0;
    __syncthreads();

    double ent = 0.0;
    for (int j = tid; j < KK; j += 256) {
        double p = (double)hist[j] / denom;
        ent += p * log(p + 1e-8);
    }
    red[tid] = ent;
    __syncthreads();
    for (int s = 128; s > 0; s >>= 1) {
        if (tid < s) red[tid] += red[tid + s];
        __syncthreads();
    }

    if (tid == 0) {
        double mse = mse_sum / (double)((size_t)NN * DD);
        out[OUT_COMMIT] = (float)(mse * 0.25);
        out[OUT_CBL]    = (float)mse;
        out[OUT_PERP]   = (float)exp(-red[0]);
    }
}

// ---------------------------------------------------------------------------
extern "C" void kernel_launch(void* const* d_in, const int* in_sizes, int n_in,
                              void* d_out, int out_size, void* d_ws, size_t ws_size,
                              hipStream_t stream) {
    const float* latents = (const float*)d_in[0];   // [16,1024,256]
    const float* mask    = (const float*)d_in[1];   // [16,1024]
    const float* cb      = (const float*)d_in[2];   // [8192,256]
    float* out = (float*)d_out;

    // workspace layout (floats): hist[8192] | partial[512] | c2[8192] | x2[16384]
    float* hist    = (float*)d_ws;
    float* partial = hist + KK;
    float* c2      = partial + NBLOCKS;
    float* x2      = c2 + KK;

    hipMemsetAsync(d_ws, 0, KK * sizeof(float), stream);   // zero histogram
    rowsumsq<<<KK / MT, 256, 0, stream>>>(cb, c2);          // numpy-exact |c|^2
    rowsumsq<<<NN / MT, 256, 0, stream>>>(latents, x2);     // numpy-exact |x|^2
    vq_main<<<NBLOCKS, 256, 0, stream>>>(latents, cb, c2, x2, mask, out, hist, partial);
    vq_finalize<<<1, 256, 0, stream>>>(partial, hist, out);
}

// Round 5
// 1388.171 us; speedup vs baseline: 3.0293x; 3.0293x over previous
//
#include <hip/hip_runtime.h>
#include <math.h>

// Problem constants
#define DD 256            // latent dim
#define KK 8192           // codebook size
#define NN 16384          // 16 * 1024 rows
#define MT 64             // rows per block
#define NT 64             // codebook cols per chunk
#define NCHUNK (KK / NT)  // 128
#define NBLOCKS (NN / MT) // 256
#define CSTRIDE 260       // 256+4 pad: 16B-aligned rows, 4-bank row skew

// Output layout (all float32, concatenated in reference return order)
#define OUT_IDS   0
#define OUT_Q     16384
#define OUT_ST    4210688          // 16384 + 4194304
#define OUT_COMMIT 8404992
#define OUT_CBL    8404993
#define OUT_PERP   8404994

// ---------------------------------------------------------------------------
// async global->LDS, 16B per lane. LDS dest is wave-uniform base + lane*16:
// one call stages one contiguous 1024B row. No VGPR round-trip -> no spills.
// ---------------------------------------------------------------------------
__device__ __forceinline__ void gl2lds16(const float* g, float* l) {
    __builtin_amdgcn_global_load_lds(
        (const __attribute__((address_space(1))) float*)g,
        (__attribute__((address_space(3))) float*)l, 16, 0, 0);
}

// ---------------------------------------------------------------------------
// numpy pairwise-sum replica for sum of squares (verified bit-exact, round 2)
// ---------------------------------------------------------------------------
__device__ __forceinline__ float np_block128_sumsq(const float* p) {
    #pragma clang fp contract(off)
    float r0 = p[0] * p[0], r1 = p[1] * p[1], r2 = p[2] * p[2], r3 = p[3] * p[3];
    float r4 = p[4] * p[4], r5 = p[5] * p[5], r6 = p[6] * p[6], r7 = p[7] * p[7];
    for (int i = 8; i < 128; i += 8) {
        r0 = r0 + p[i + 0] * p[i + 0];
        r1 = r1 + p[i + 1] * p[i + 1];
        r2 = r2 + p[i + 2] * p[i + 2];
        r3 = r3 + p[i + 3] * p[i + 3];
        r4 = r4 + p[i + 4] * p[i + 4];
        r5 = r5 + p[i + 5] * p[i + 5];
        r6 = r6 + p[i + 6] * p[i + 6];
        r7 = r7 + p[i + 7] * p[i + 7];
    }
    return ((r0 + r1) + (r2 + r3)) + ((r4 + r5) + (r6 + r7));
}

__device__ __forceinline__ float np_pairwise256_sumsq(const float* a) {
    #pragma clang fp contract(off)
    float s0 = np_block128_sumsq(a);
    float s1 = np_block128_sumsq(a + 128);
    return s0 + s1;
}

// ---------------------------------------------------------------------------
// Kernel 1: per-row sum of squares, numpy-pairwise-exact (unchanged, verified)
// ---------------------------------------------------------------------------
__global__ __launch_bounds__(256) void rowsumsq(const float* __restrict__ A,
                                                float* __restrict__ out) {
    __shared__ __align__(16) float sA[MT][CSTRIDE];
    const int tid = threadIdx.x;
    const int base = blockIdx.x * MT;
    #pragma unroll
    for (int i = 0; i < 16; ++i) {
        int g = i * 256 + tid;
        int row = g >> 6, d4 = g & 63;
        float4 v = reinterpret_cast<const float4*>(A)[(size_t)(base + row) * (DD / 4) + d4];
        *reinterpret_cast<float4*>(&sA[row][d4 * 4]) = v;
    }
    __syncthreads();
    if (tid < MT) out[base + tid] = np_pairwise256_sumsq(sA[tid]);
}

// ---------------------------------------------------------------------------
// Kernel 2: main VQ kernel. 256 blocks x 256 threads, 1 block/CU (142KB LDS).
//   Both operands in LDS (X reads = 16-lane broadcasts, ~free unique bytes).
//   4x4 register tile/thread: 8 ds_read_b128 per d4-step for 64 wave-fmas
//   (128 VALU-cyc) -> VALU-bound. Staging via global_load_lds (async, no
//   VGPR round-trip -> no spills; round-1's pf[16] spill bug is gone).
//   Distance pipeline bit-identical to the verified round-2 kernel:
//     m: in-order fp32 fma chain d=0..255;  d = fl(fl(x2+c2) - 2m);
//     argmin with first-index tie-break.
// ---------------------------------------------------------------------------
__global__ __launch_bounds__(256, 1) void vq_main(const float* __restrict__ X,
                                                  const float* __restrict__ CB,
                                                  const float* __restrict__ c2,
                                                  const float* __restrict__ x2,
                                                  const float* __restrict__ mask,
                                                  float* __restrict__ out,
                                                  float* __restrict__ hist,
                                                  float* __restrict__ partial) {
    __shared__ __align__(16) float sX[MT][CSTRIDE];   // 66560 B
    __shared__ __align__(16) float sC[NT][CSTRIDE];   // 66560 B
    __shared__ float red_s[MT][17];
    __shared__ int   red_i[MT][17];
    __shared__ int   row_id[MT];
    __shared__ float wsum[4];

    const int tid  = threadIdx.x;
    const int lane = tid & 63;
    const int widu = __builtin_amdgcn_readfirstlane(tid >> 6);  // uniform wave id
    const int tx = tid & 15;    // col group: cols tx + 16*j
    const int ty = tid >> 4;    // row group: rows ty + 16*r   (ty 0..15)
    const int block_row = blockIdx.x * MT;

    // ---- stage X tile (once) + codebook chunk 0, all via async LDS-DMA ----
    #pragma unroll
    for (int i = 0; i < 16; ++i) {
        int row = widu * 16 + i;
        gl2lds16(X + (size_t)(block_row + row) * DD + lane * 4, &sX[row][0]);
    }
    #pragma unroll
    for (int i = 0; i < 16; ++i) {
        int n = widu * 16 + i;
        gl2lds16(CB + (size_t)n * DD + lane * 4, &sC[n][0]);
    }

    // per-thread row constants (loaded once; broadcast vector loads)
    float x2r[4];
    #pragma unroll
    for (int r = 0; r < 4; ++r) x2r[r] = x2[block_row + ty + 16 * r];

    __syncthreads();   // drains vmcnt -> sX + sC chunk 0 resident

    float best[4];
    int   besti[4];
    #pragma unroll
    for (int r = 0; r < 4; ++r) { best[r] = 3.4e38f; besti[r] = 0; }

    for (int chunk = 0; chunk < NCHUNK; ++chunk) {
        const int col0 = chunk * NT;

        float c2v[4];
        #pragma unroll
        for (int j = 0; j < 4; ++j) c2v[j] = c2[col0 + tx + 16 * j];

        float acc[4][4];
        #pragma unroll
        for (int r = 0; r < 4; ++r)
            #pragma unroll
            for (int j = 0; j < 4; ++j) acc[r][j] = 0.0f;

        // in-order fma chain per (row,col) over d=0..255: bit-exact core
        #pragma unroll 4
        for (int d4 = 0; d4 < DD / 4; ++d4) {
            float4 xr[4], cc[4];
            #pragma unroll
            for (int r = 0; r < 4; ++r)
                xr[r] = *reinterpret_cast<const float4*>(&sX[ty + 16 * r][d4 * 4]);
            #pragma unroll
            for (int j = 0; j < 4; ++j)
                cc[j] = *reinterpret_cast<const float4*>(&sC[tx + 16 * j][d4 * 4]);
            #pragma unroll
            for (int r = 0; r < 4; ++r)
                #pragma unroll
                for (int j = 0; j < 4; ++j) {
                    acc[r][j] = fmaf(xr[r].x, cc[j].x, acc[r][j]);
                    acc[r][j] = fmaf(xr[r].y, cc[j].y, acc[r][j]);
                    acc[r][j] = fmaf(xr[r].z, cc[j].z, acc[r][j]);
                    acc[r][j] = fmaf(xr[r].w, cc[j].w, acc[r][j]);
                }
        }

        // fp32 distance exactly as numpy: fl(fl(x2+c2) - 2m), first-index ties
        #pragma unroll
        for (int r = 0; r < 4; ++r) {
            #pragma unroll
            for (int j = 0; j < 4; ++j) {
                int col = col0 + tx + 16 * j;
                float t1 = x2r[r] + c2v[j];
                float s  = t1 - 2.0f * acc[r][j];
                if (s < best[r] || (s == best[r] && col < besti[r])) {
                    best[r] = s; besti[r] = col;
                }
            }
        }

        __syncthreads();   // all waves done reading sC
        if (chunk + 1 < NCHUNK) {
            const int ncol0 = (chunk + 1) * NT;
            #pragma unroll
            for (int i = 0; i < 16; ++i) {
                int n = widu * 16 + i;
                gl2lds16(CB + (size_t)(ncol0 + n) * DD + lane * 4, &sC[n][0]);
            }
        }
        __syncthreads();   // vmcnt(0) drain -> next chunk resident
    }

    // ---- cross-thread argmin reduction: 16 tx candidates per row ----
    #pragma unroll
    for (int r = 0; r < 4; ++r) {
        red_s[ty + 16 * r][tx] = best[r];
        red_i[ty + 16 * r][tx] = besti[r];
    }
    __syncthreads();
    if (tid < MT) {
        int row = tid;
        float b = red_s[row][0];
        int  bi = red_i[row][0];
        #pragma unroll
        for (int t = 1; t < 16; ++t) {
            float s = red_s[row][t];
            int  i2 = red_i[row][t];
            if (s < b || (s == b && i2 < bi)) { b = s; bi = i2; }
        }
        row_id[row] = bi;
        out[OUT_IDS + block_row + row] = (float)bi;
        atomicAdd(&hist[bi], mask[block_row + row]);
    }
    __syncthreads();

    // ---- fused gather: quantized, st_quantized, MSE partial ----
    float msep = 0.0f;
    float* outq  = out + OUT_Q;
    float* outst = out + OUT_ST;
    #pragma unroll
    for (int i = 0; i < 16; ++i) {
        int g = i * 256 + tid;
        int row = g >> 6;
        int d4  = g & 63;
        int id = row_id[row];
        float4 q = reinterpret_cast<const float4*>(CB)[(size_t)id * (DD / 4) + d4];
        float4 x = *reinterpret_cast<const float4*>(&sX[row][d4 * 4]);
        float4 st;
        st.x = x.x + (q.x - x.x);
        st.y = x.y + (q.y - x.y);
        st.z = x.z + (q.z - x.z);
        st.w = x.w + (q.w - x.w);
        float dx = x.x - q.x; msep = fmaf(dx, dx, msep);
        dx = x.y - q.y; msep = fmaf(dx, dx, msep);
        dx = x.z - q.z; msep = fmaf(dx, dx, msep);
        dx = x.w - q.w; msep = fmaf(dx, dx, msep);
        size_t o = (size_t)(block_row + row) * (DD / 4) + d4;
        reinterpret_cast<float4*>(outq)[o]  = q;
        reinterpret_cast<float4*>(outst)[o] = st;
    }
    #pragma unroll
    for (int off = 32; off > 0; off >>= 1) msep += __shfl_down(msep, off, 64);
    if (lane == 0) wsum[tid >> 6] = msep;
    __syncthreads();
    if (tid == 0) partial[blockIdx.x] = wsum[0] + wsum[1] + wsum[2] + wsum[3];
}

// ---------------------------------------------------------------------------
// Kernel 3: finalize losses + perplexity (double precision, single block)
// ---------------------------------------------------------------------------
__global__ __launch_bounds__(256) void vq_finalize(const float* __restrict__ partial,
                                                   const float* __restrict__ hist,
                                                   float* __restrict__ out) {
    __shared__ double red[256];
    const int tid = threadIdx.x;

    double ps = 0.0;
    for (int j = tid; j < NBLOCKS; j += 256) ps += (double)partial[j];
    red[tid] = ps;
    __syncthreads();
    for (int s = 128; s > 0; s >>= 1) {
        if (tid < s) red[tid] += red[tid + s];
        __syncthreads();
    }
    double mse_sum = red[0];
    __syncthreads();

    double hs = 0.0;
    for (int j = tid; j < KK; j += 256) hs += (double)hist[j];
    red[tid] = hs;
    __syncthreads();
    for (int s = 128; s > 0; s >>= 1) {
        if (tid < s) red[tid] += red[tid + s];
        __syncthreads();
    }
    double denom = red[0] > 1.0 ? red[0] : 1.0;
    __syncthreads();

    double ent = 0.0;
    for (int j = tid; j < KK; j += 256) {
        double p = (double)hist[j] / denom;
        ent += p * log(p + 1e-8);
    }
    red[tid] = ent;
    __syncthreads();
    for (int s = 128; s > 0; s >>= 1) {
        if (tid < s) red[tid] += red[tid + s];
        __syncthreads();
    }

    if (tid == 0) {
        double mse = mse_sum / (double)((size_t)NN * DD);
        out[OUT_COMMIT] = (float)(mse * 0.25);
        out[OUT_CBL]    = (float)mse;
        out[OUT_PERP]   = (float)exp(-red[0]);
    }
}

// ---------------------------------------------------------------------------
extern "C" void kernel_launch(void* const* d_in, const int* in_sizes, int n_in,
                              void* d_out, int out_size, void* d_ws, size_t ws_size,
                              hipStream_t stream) {
    const float* latents = (const float*)d_in[0];   // [16,1024,256]
    const float* mask    = (const float*)d_in[1];   // [16,1024]
    const float* cb      = (const float*)d_in[2];   // [8192,256]
    float* out = (float*)d_out;

    // workspace layout (floats): hist[8192] | partial[256] | c2[8192] | x2[16384]
    float* hist    = (float*)d_ws;
    float* partial = hist + KK;
    float* c2      = partial + NBLOCKS;
    float* x2      = c2 + KK;

    hipMemsetAsync(d_ws, 0, KK * sizeof(float), stream);   // zero histogram
    rowsumsq<<<KK / MT, 256, 0, stream>>>(cb, c2);          // numpy-exact |c|^2
    rowsumsq<<<NN / MT, 256, 0, stream>>>(latents, x2);     // numpy-exact |x|^2
    vq_main<<<NBLOCKS, 256, 0, stream>>>(latents, cb, c2, x2, mask, out, hist, partial);
    vq_finalize<<<1, 256, 0, stream>>>(partial, hist, out);
}

// Round 6
// 1196.210 us; speedup vs baseline: 3.5155x; 1.1605x over previous
//
#include <hip/hip_runtime.h>
#include <math.h>

// Problem constants
#define DD 256            // latent dim
#define KK 8192           // codebook size
#define NN 16384          // 16 * 1024 rows
#define MT 64             // rows per block
#define NT 256            // codebook cols per chunk
#define NCH (KK / NT)     // 32 chunks
#define DT 32             // d-slice floats
#define NDT (DD / DT)     // 8 d-slices
#define NBLOCKS (NN / MT) // 256
#define SROW 36           // slice-row stride in floats (32 data + 4 pad = 144 B)
#define XSLICE (MT * SROW)    // 2304 floats per X slice (9216 B)
#define CSLICE (NT * SROW)    // 9216 floats per C slice (36864 B)
#define RSTRIDE 260       // rowsumsq staging stride (unchanged, verified)

// Output layout (all float32, concatenated in reference return order)
#define OUT_IDS   0
#define OUT_Q     16384
#define OUT_ST    4210688          // 16384 + 4194304
#define OUT_COMMIT 8404992
#define OUT_CBL    8404993
#define OUT_PERP   8404994

// ---------------------------------------------------------------------------
// async global->LDS DMA: lane i's 16B lands at ldsbase + i*16 (contiguous 1KB)
// ---------------------------------------------------------------------------
__device__ __forceinline__ void gl2lds16(const float* g, float* l) {
    __builtin_amdgcn_global_load_lds(
        (const __attribute__((address_space(1))) float*)g,
        (__attribute__((address_space(3))) float*)l, 16, 0, 0);
}

// ---------------------------------------------------------------------------
// numpy pairwise-sum replica for sum of squares (verified bit-exact, round 2)
// ---------------------------------------------------------------------------
__device__ __forceinline__ float np_block128_sumsq(const float* p) {
    #pragma clang fp contract(off)
    float r0 = p[0] * p[0], r1 = p[1] * p[1], r2 = p[2] * p[2], r3 = p[3] * p[3];
    float r4 = p[4] * p[4], r5 = p[5] * p[5], r6 = p[6] * p[6], r7 = p[7] * p[7];
    for (int i = 8; i < 128; i += 8) {
        r0 = r0 + p[i + 0] * p[i + 0];
        r1 = r1 + p[i + 1] * p[i + 1];
        r2 = r2 + p[i + 2] * p[i + 2];
        r3 = r3 + p[i + 3] * p[i + 3];
        r4 = r4 + p[i + 4] * p[i + 4];
        r5 = r5 + p[i + 5] * p[i + 5];
        r6 = r6 + p[i + 6] * p[i + 6];
        r7 = r7 + p[i + 7] * p[i + 7];
    }
    return ((r0 + r1) + (r2 + r3)) + ((r4 + r5) + (r6 + r7));
}

__device__ __forceinline__ float np_pairwise256_sumsq(const float* a) {
    #pragma clang fp contract(off)
    float s0 = np_block128_sumsq(a);
    float s1 = np_block128_sumsq(a + 128);
    return s0 + s1;
}

// ---------------------------------------------------------------------------
// Kernel 1: per-row sum of squares, numpy-pairwise-exact (unchanged, verified)
// ---------------------------------------------------------------------------
__global__ __launch_bounds__(256) void rowsumsq(const float* __restrict__ A,
                                                float* __restrict__ out) {
    __shared__ __align__(16) float sA[MT][RSTRIDE];
    const int tid = threadIdx.x;
    const int base = blockIdx.x * MT;
    #pragma unroll
    for (int i = 0; i < 16; ++i) {
        int g = i * 256 + tid;
        int row = g >> 6, d4 = g & 63;
        float4 v = reinterpret_cast<const float4*>(A)[(size_t)(base + row) * (DD / 4) + d4];
        *reinterpret_cast<float4*>(&sA[row][d4 * 4]) = v;
    }
    __syncthreads();
    if (tid < MT) out[base + tid] = np_pairwise256_sumsq(sA[tid]);
}

// ---------------------------------------------------------------------------
// Kernel 2: main VQ kernel. 256 blocks x 256 threads, 1 block/CU.
//   D-sliced LDS: X fully resident as 8 slices (staged once via DMA);
//   C streamed as 256-col x 32-float slices, double-buffered, DMA'd with a
//   stride-144B hole layout (flat f16 -> row=f16/9, rem=f16%9, rem==8 = pad).
//   8x8 register tile/thread: 16 ds_read_b128 per d4-step for 256 wave-fmas
//   (512 VALU-cyc) -> DS-balanced at ~128 B/cyc/CU.
//   fp32 fma chain per (row,col) strictly d=0..255 across slices: bit-exact,
//   score fl(fl(x2+c2)-2m) + first-index ties (verified round 2).
// ---------------------------------------------------------------------------
__global__ __launch_bounds__(256, 1) void vq_main(const float* __restrict__ X,
                                                  const float* __restrict__ CB,
                                                  const float* __restrict__ c2,
                                                  const float* __restrict__ x2,
                                                  const float* __restrict__ mask,
                                                  float* __restrict__ out,
                                                  float* __restrict__ hist,
                                                  float* __restrict__ partial) {
    __shared__ __align__(16) float sX[NDT * XSLICE];  // 73728 B
    __shared__ __align__(16) float sC[2 * CSLICE];    // 73728 B
    __shared__ int   row_id[MT];
    __shared__ float wsum[4];

    const int tid  = threadIdx.x;
    const int lane = tid & 63;
    const int widu = __builtin_amdgcn_readfirstlane(tid >> 6);  // uniform wave id
    const int tx = tid & 31;      // col group: cols tx + 32*j   (j 0..7)
    const int ty = tid >> 5;      // row group: rows ty*8 + rr   (rr 0..7)
    const int block_row = blockIdx.x * MT;

    // ---- stage ALL X slices once: 72 KB-calls; wave w does call = w + 4*k ----
    #pragma unroll
    for (int k = 0; k < 18; ++k) {
        unsigned call = widu + 4u * k;
        unsigned f16  = call * 64u + lane;
        unsigned dtrow = f16 / 9u;           // 0..511
        unsigned rem   = f16 - dtrow * 9u;   // 0..8 (8 = pad)
        unsigned dt  = dtrow >> 6;
        unsigned row = dtrow & 63u;
        size_t gidx = (rem < 8u) ? ((size_t)(block_row + row) * DD + dt * DT + rem * 4u)
                                 : (size_t)0;
        gl2lds16(X + gidx, &sX[call * 256]);
    }
    // ---- stage C chunk 0, dtile 0 into buf 0: 36 calls ----
    #pragma unroll
    for (int k = 0; k < 9; ++k) {
        unsigned call = widu + 4u * k;
        unsigned f16  = call * 64u + lane;
        unsigned col  = f16 / 9u;            // 0..255
        unsigned rem  = f16 - col * 9u;
        size_t gidx = (rem < 8u) ? ((size_t)col * DD + rem * 4u) : (size_t)0;
        gl2lds16(CB + gidx, &sC[call * 256]);
    }

    // per-thread row constants (bit-identical to numpy's)
    float x2r[8];
    #pragma unroll
    for (int rr = 0; rr < 8; ++rr) x2r[rr] = x2[block_row + ty * 8 + rr];

    __syncthreads();   // drains vmcnt -> sX + sC buf0 resident

    float best[8];
    int   besti[8];
    #pragma unroll
    for (int rr = 0; rr < 8; ++rr) { best[rr] = 3.4e38f; besti[rr] = 0; }

    for (int chunk = 0; chunk < NCH; ++chunk) {
        const int col0 = chunk * NT;

        float c2v[8];
        #pragma unroll
        for (int j = 0; j < 8; ++j) c2v[j] = c2[col0 + tx + 32 * j];

        float acc[8][8];
        #pragma unroll
        for (int rr = 0; rr < 8; ++rr)
            #pragma unroll
            for (int j = 0; j < 8; ++j) acc[rr][j] = 0.0f;

        for (int dt = 0; dt < NDT; ++dt) {
            const int it = chunk * NDT + dt;

            // ---- stage next C slice into the other buffer (async, overlaps) ----
            if (it + 1 < NCH * NDT) {
                const int nit  = it + 1;
                const int nch  = nit >> 3;
                const int ndtl = nit & 7;
                float* dst = &sC[(nit & 1) * CSLICE];
                #pragma unroll
                for (int k = 0; k < 9; ++k) {
                    unsigned call = widu + 4u * k;
                    unsigned f16  = call * 64u + lane;
                    unsigned col  = f16 / 9u;
                    unsigned rem  = f16 - col * 9u;
                    size_t gidx = (rem < 8u)
                        ? ((size_t)(nch * NT + col) * DD + ndtl * DT + rem * 4u)
                        : (size_t)0;
                    gl2lds16(CB + gidx, dst + call * 256);
                }
            }

            // ---- compute on current buffer ----
            const float* cb_ = &sC[(it & 1) * CSLICE] + tx * SROW;
            const float* xb_ = &sX[dt * XSLICE] + (ty * 8) * SROW;
            #pragma unroll 2
            for (int d4 = 0; d4 < DT / 4; ++d4) {
                float4 cc[8], xr[8];
                #pragma unroll
                for (int j = 0; j < 8; ++j)
                    cc[j] = *reinterpret_cast<const float4*>(cb_ + j * 32 * SROW + d4 * 4);
                #pragma unroll
                for (int rr = 0; rr < 8; ++rr)
                    xr[rr] = *reinterpret_cast<const float4*>(xb_ + rr * SROW + d4 * 4);
                #pragma unroll
                for (int rr = 0; rr < 8; ++rr)
                    #pragma unroll
                    for (int j = 0; j < 8; ++j) {
                        acc[rr][j] = fmaf(xr[rr].x, cc[j].x, acc[rr][j]);
                        acc[rr][j] = fmaf(xr[rr].y, cc[j].y, acc[rr][j]);
                        acc[rr][j] = fmaf(xr[rr].z, cc[j].z, acc[rr][j]);
                        acc[rr][j] = fmaf(xr[rr].w, cc[j].w, acc[rr][j]);
                    }
            }
            __syncthreads();   // waves done reading buf; next-slice DMA drained
        }

        // ---- fp32 distance exactly as numpy, then argmin (first-index ties) ----
        #pragma unroll
        for (int rr = 0; rr < 8; ++rr) {
            #pragma unroll
            for (int j = 0; j < 8; ++j) {
                int col = col0 + tx + 32 * j;
                float t1 = x2r[rr] + c2v[j];
                float s  = t1 - 2.0f * acc[rr][j];
                if (s < best[rr] || (s == best[rr] && col < besti[rr])) {
                    best[rr] = s; besti[rr] = col;
                }
            }
        }
    }

    // ---- argmin across the 32 col-lanes (xor butterfly within 32-group) ----
    #pragma unroll
    for (int rr = 0; rr < 8; ++rr) {
        float b = best[rr];
        int  bi = besti[rr];
        #pragma unroll
        for (int m = 16; m > 0; m >>= 1) {
            float b2 = __shfl_xor(b, m, 64);   // lane^m stays within 32-group
            int   i2 = __shfl_xor(bi, m, 64);
            if (b2 < b || (b2 == b && i2 < bi)) { b = b2; bi = i2; }
        }
        if (tx == 0) row_id[ty * 8 + rr] = bi;
    }
    __syncthreads();

    if (tid < MT) {
        int bi = row_id[tid];
        out[OUT_IDS + block_row + tid] = (float)bi;
        atomicAdd(&hist[bi], mask[block_row + tid]);
    }

    // ---- fused gather: quantized, st_quantized, MSE partial (x from global) ----
    float msep = 0.0f;
    float* outq  = out + OUT_Q;
    float* outst = out + OUT_ST;
    #pragma unroll
    for (int i = 0; i < 16; ++i) {
        int g = i * 256 + tid;
        int row = g >> 6;
        int d4  = g & 63;
        int id = row_id[row];
        float4 q = reinterpret_cast<const float4*>(CB)[(size_t)id * (DD / 4) + d4];
        float4 x = reinterpret_cast<const float4*>(X)[(size_t)(block_row + row) * (DD / 4) + d4];
        float4 st;
        st.x = x.x + (q.x - x.x);
        st.y = x.y + (q.y - x.y);
        st.z = x.z + (q.z - x.z);
        st.w = x.w + (q.w - x.w);
        float dx = x.x - q.x; msep = fmaf(dx, dx, msep);
        dx = x.y - q.y; msep = fmaf(dx, dx, msep);
        dx = x.z - q.z; msep = fmaf(dx, dx, msep);
        dx = x.w - q.w; msep = fmaf(dx, dx, msep);
        size_t o = (size_t)(block_row + row) * (DD / 4) + d4;
        reinterpret_cast<float4*>(outq)[o]  = q;
        reinterpret_cast<float4*>(outst)[o] = st;
    }
    #pragma unroll
    for (int off = 32; off > 0; off >>= 1) msep += __shfl_down(msep, off, 64);
    if (lane == 0) wsum[tid >> 6] = msep;
    __syncthreads();
    if (tid == 0) partial[blockIdx.x] = wsum[0] + wsum[1] + wsum[2] + wsum[3];
}

// ---------------------------------------------------------------------------
// Kernel 3: finalize losses + perplexity (double precision, single block)
// ---------------------------------------------------------------------------
__global__ __launch_bounds__(256) void vq_finalize(const float* __restrict__ partial,
                                                   const float* __restrict__ hist,
                                                   float* __restrict__ out) {
    __shared__ double red[256];
    const int tid = threadIdx.x;

    double ps = 0.0;
    for (int j = tid; j < NBLOCKS; j += 256) ps += (double)partial[j];
    red[tid] = ps;
    __syncthreads();
    for (int s = 128; s > 0; s >>= 1) {
        if (tid < s) red[tid] += red[tid + s];
        __syncthreads();
    }
    double mse_sum = red[0];
    __syncthreads();

    double hs = 0.0;
    for (int j = tid; j < KK; j += 256) hs += (double)hist[j];
    red[tid] = hs;
    __syncthreads();
    for (int s = 128; s > 0; s >>= 1) {
        if (tid < s) red[tid] += red[tid + s];
        __syncthreads();
    }
    double denom = red[0] > 1.0 ? red[0] : 1.0;
    __syncthreads();

    double ent = 0.0;
    for (int j = tid; j < KK; j += 256) {
        double p = (double)hist[j] / denom;
        ent += p * log(p + 1e-8);
    }
    red[tid] = ent;
    __syncthreads();
    for (int s = 128; s > 0; s >>= 1) {
        if (tid < s) red[tid] += red[tid + s];
        __syncthreads();
    }

    if (tid == 0) {
        double mse = mse_sum / (double)((size_t)NN * DD);
        out[OUT_COMMIT] = (float)(mse * 0.25);
        out[OUT_CBL]    = (float)mse;
        out[OUT_PERP]   = (float)exp(-red[0]);
    }
}

// ---------------------------------------------------------------------------
extern "C" void kernel_launch(void* const* d_in, const int* in_sizes, int n_in,
                              void* d_out, int out_size, void* d_ws, size_t ws_size,
                              hipStream_t stream) {
    const float* latents = (const float*)d_in[0];   // [16,1024,256]
    const float* mask    = (const float*)d_in[1];   // [16,1024]
    const float* cb      = (const float*)d_in[2];   // [8192,256]
    float* out = (float*)d_out;

    // workspace layout (floats): hist[8192] | partial[256] | c2[8192] | x2[16384]
    float* hist    = (float*)d_ws;
    float* partial = hist + KK;
    float* c2      = partial + NBLOCKS;
    float* x2      = c2 + KK;

    hipMemsetAsync(d_ws, 0, KK * sizeof(float), stream);   // zero histogram
    rowsumsq<<<KK / MT, 256, 0, stream>>>(cb, c2);          // numpy-exact |c|^2
    rowsumsq<<<NN / MT, 256, 0, stream>>>(latents, x2);     // numpy-exact |x|^2
    vq_main<<<NBLOCKS, 256, 0, stream>>>(latents, cb, c2, x2, mask, out, hist, partial);
    vq_finalize<<<1, 256, 0, stream>>>(partial, hist, out);
}